// Round 6
// baseline (2887.329 us; speedup 1.0000x reference)
//
#include <hip/hip_runtime.h>
#include <hip/hip_fp16.h>
#include <math.h>

// GCNII forward, fp16-compressed intermediates.
//   h0 = relu(x @ Wlin + b)                       [lin0: tiled GEMM]
//   per layer l: z = 0.9*(A@h) + 0.1*x0           [spmm: coarse buckets + LDS f32 atomics]
//                h = relu(z @ W'_l)               [dense: tiled GEMM]
//   W'_l = (1-beta_l) I + beta_l W_l (premixed).
// Edge prep: ONE pass partitions edges into 782 destination-range buckets
// (128 nodes each) with oversized fixed slots (atomic append). No per-node
// sort, no hist/scan/scatter: the SpMM block owns a bucket and accumulates
// into LDS zs[128][65] f32 via ds_add_f32, so record order is irrelevant.
// This removes the random-8B-scatter write amplification entirely.
// Constants: N=100000, E=1600000, H=128, D=64, L=4.

#define DD 64
#define HH 128
#define M_TILE 128
#define K_CHUNK 32
#define NPB 128            // nodes per bucket (bucket = node>>7)
#define SLOT 2560          // record slots per bucket (mean ~2046, +11 sigma)
#define NB_MAX 1024
#define PART_BLOCKS 256

__device__ inline ushort f2h(float f) { return __half_as_ushort(__float2half(f)); }
__device__ inline float us2f(ushort u) { return __half2float(__ushort_as_half(u)); }

__global__ __launch_bounds__(256) void init_bcur(int* bcur, int nb) {
    int i = blockIdx.x * blockDim.x + threadIdx.x;
    if (i < nb) bcur[i] = i * SLOT;
}

// One-pass partition into bucket slots. Record: {row:17 | col_lo15:15},
// {col_hi2:2 | w_fp16:16<<2}. Per-block LDS counting + one slot reservation
// per (block,bucket), then bucket-local sequential runs (~8 records each).
// Chunk ids swizzled so each XCD handles a contiguous chunk range (seam
// lines between runs of the same XCD stay in its L2).
__global__ __launch_bounds__(256) void partition_kernel(
    const int* __restrict__ row, const int* __restrict__ col,
    const float* __restrict__ ew, int* __restrict__ bcur,
    uint2* __restrict__ pk, int E, int nb) {
    __shared__ int cnt[NB_MAX], base[NB_MAX], rc[NB_MAX];
    int t = threadIdx.x;
    for (int i = t; i < nb; i += 256) { cnt[i] = 0; rc[i] = 0; }
    __syncthreads();
    int cid = ((blockIdx.x & 7) << 5) | (blockIdx.x >> 3);
    int chunk = (E + PART_BLOCKS - 1) / PART_BLOCKS;
    int s0 = cid * chunk;
    int s1 = min(s0 + chunk, E);
    for (int e = s0 + t; e < s1; e += 256) atomicAdd(&cnt[row[e] >> 7], 1);
    __syncthreads();
    for (int i = t; i < nb; i += 256)
        if (cnt[i] > 0) base[i] = atomicAdd(&bcur[i], cnt[i]);
    __syncthreads();
    for (int e = s0 + t; e < s1; e += 256) {
        int r = row[e];
        int c = col[e];
        ushort wh = f2h(ew[e]);
        int b = r >> 7;
        int pos = base[b] + atomicAdd(&rc[b], 1);
        if (pos < (b + 1) * SLOT)   // defensive (slot is +11 sigma, never hits)
            pk[pos] = make_uint2((uint)r | (((uint)c & 0x7fffu) << 17),
                                 ((uint)c >> 15) | ((uint)wh << 2));
    }
}

// W'_l = (1-beta_l) I + beta_l W_l, all L layers at once.
__global__ __launch_bounds__(256) void prep_w(const float* __restrict__ conv_w,
                                              float* __restrict__ Wp, int total) {
    int i = blockIdx.x * blockDim.x + threadIdx.x;
    if (i >= total) return;
    int l = i >> 12;
    int r = i & 4095;
    int d = r >> 6, j = r & 63;
    float beta = logf(0.5f / (float)(l + 1) + 1.0f);
    float v = beta * conv_w[i];
    if (d == j) v += 1.0f - beta;
    Wp[i] = v;
}

// h0 = relu(x @ Wlin + b). Register-tiled GEMM. Writes x0, h (half).
__global__ __launch_bounds__(256) void lin0_kernel(
    const float* __restrict__ x, const float* __restrict__ Wlin,
    const float* __restrict__ b, ushort* __restrict__ x0,
    ushort* __restrict__ h, int n) {
    __shared__ float Ws[HH * DD];              // 32 KB
    __shared__ float xs[K_CHUNK][M_TILE + 4];
    for (int i = threadIdx.x; i < HH * DD; i += 256) Ws[i] = Wlin[i];

    int t = threadIdx.x;
    int tm = t >> 4, tn = t & 15;
    int m0 = blockIdx.x * M_TILE;

    float4 bb = *(const float4*)&b[tn * 4];
    float acc[8][4];
#pragma unroll
    for (int mi = 0; mi < 8; ++mi) {
        acc[mi][0] = bb.x; acc[mi][1] = bb.y; acc[mi][2] = bb.z; acc[mi][3] = bb.w;
    }

    for (int kk = 0; kk < HH; kk += K_CHUNK) {
        __syncthreads();
#pragma unroll
        for (int i = 0; i < 4; ++i) {
            int s = t + i * 256;
            int node = s >> 3;
            int cpos = (s & 7) * 4;
            int g = m0 + node;
            float4 v = make_float4(0.f, 0.f, 0.f, 0.f);
            if (g < n) v = *(const float4*)&x[(size_t)g * HH + kk + cpos];
            xs[cpos + 0][node] = v.x;
            xs[cpos + 1][node] = v.y;
            xs[cpos + 2][node] = v.z;
            xs[cpos + 3][node] = v.w;
        }
        __syncthreads();
#pragma unroll
        for (int k = 0; k < K_CHUNK; ++k) {
            float4 wv = *(const float4*)&Ws[(kk + k) * DD + tn * 4];
            const float* xr = &xs[k][tm * 8];
            float4 xa = *(const float4*)xr;
            float4 xb = *(const float4*)(xr + 4);
            float xm[8] = {xa.x, xa.y, xa.z, xa.w, xb.x, xb.y, xb.z, xb.w};
            float wj[4] = {wv.x, wv.y, wv.z, wv.w};
#pragma unroll
            for (int mi = 0; mi < 8; ++mi)
#pragma unroll
                for (int j = 0; j < 4; ++j)
                    acc[mi][j] += xm[mi] * wj[j];
        }
    }
#pragma unroll
    for (int mi = 0; mi < 8; ++mi) {
        int node = m0 + tm * 8 + mi;
        if (node >= n) continue;
        ushort4 o;
        o.x = f2h(fmaxf(acc[mi][0], 0.f));
        o.y = f2h(fmaxf(acc[mi][1], 0.f));
        o.z = f2h(fmaxf(acc[mi][2], 0.f));
        o.w = f2h(fmaxf(acc[mi][3], 0.f));
        *(ushort4*)&x0[(size_t)node * DD + tn * 4] = o;
        *(ushort4*)&h[(size_t)node * DD + tn * 4] = o;
    }
}

// SpMM + residual: z = 0.9*(A@h) + 0.1*x0 (fp16 storage, f32 accumulate).
// Block = bucket (128 nodes). zs[128][65] f32 in LDS (pad 65: bank spread).
// Waves stage 64 records; each 16-lane group processes 16 records: one
// coalesced 128B gather of h[col] per record, then 4 ds_add_f32 per lane.
// Record order within a bucket is irrelevant (atomic accumulate).
__global__ __launch_bounds__(512) void spmm_kernel(
    const ushort* __restrict__ h_in, const ushort* __restrict__ x0,
    const uint2* __restrict__ pk, const int* __restrict__ bcur,
    ushort* __restrict__ z, int n) {
    __shared__ float zs[NPB][DD + 1];   // 33.3 KB
    __shared__ uint2 es[8][64];         // 4 KB
    int b = blockIdx.x;
    int lo = b << 7;
    int cnt = bcur[b] - b * SLOT;
    const uint2* rec = pk + (size_t)b * SLOT;
    int t = threadIdx.x;
    for (int i = t; i < NPB * (DD + 1); i += 512) ((float*)zs)[i] = 0.f;
    __syncthreads();

    int wave = t >> 6, lane = t & 63, grp = lane >> 4, sub = lane & 15;
    for (int base = wave * 64; base < cnt; base += 512) {
        int m = cnt - base;
        if (m > 64) m = 64;
        if (lane < m) es[wave][lane] = rec[base + lane];
        // same-wave LDS write->read; compiler orders via lgkmcnt
        int k0 = grp * 16;
        int mg = m - k0;
        if (mg > 16) mg = 16;
#pragma unroll 4
        for (int j = 0; j < mg; ++j) {
            uint2 r2 = es[wave][k0 + j];
            int r = (int)(r2.x & 0x1ffffu);
            int c = (int)((r2.x >> 17) | ((r2.y & 3u) << 15));
            float w = us2f((ushort)((r2.y >> 2) & 0xffffu));
            uint2 hv = *(const uint2*)&h_in[(size_t)c * DD + sub * 4];
            float* zr = &zs[r - lo][sub * 4];
            atomicAdd(&zr[0], w * us2f((ushort)(hv.x & 0xffffu)));
            atomicAdd(&zr[1], w * us2f((ushort)(hv.x >> 16)));
            atomicAdd(&zr[2], w * us2f((ushort)(hv.y & 0xffffu)));
            atomicAdd(&zr[3], w * us2f((ushort)(hv.y >> 16)));
        }
    }
    __syncthreads();

    // finalize: z = 0.9*acc + 0.1*x0, pack fp16, coalesced store
    for (int u = t; u < NPB * (DD / 4); u += 512) {
        int node = u >> 4;
        int f4 = (u & 15) * 4;
        int g = lo + node;
        if (g < n) {
            uint2 xv = *(const uint2*)&x0[(size_t)g * DD + f4];
            float z0 = 0.9f * zs[node][f4 + 0] + 0.1f * us2f((ushort)(xv.x & 0xffffu));
            float z1 = 0.9f * zs[node][f4 + 1] + 0.1f * us2f((ushort)(xv.x >> 16));
            float z2 = 0.9f * zs[node][f4 + 2] + 0.1f * us2f((ushort)(xv.y & 0xffffu));
            float z3 = 0.9f * zs[node][f4 + 3] + 0.1f * us2f((ushort)(xv.y >> 16));
            uint zlo = (uint)f2h(z0) | ((uint)f2h(z1) << 16);
            uint zhi = (uint)f2h(z2) | ((uint)f2h(z3) << 16);
            *(uint2*)&z[(size_t)g * DD + f4] = make_uint2(zlo, zhi);
        }
    }
}

// h = relu(z @ W'). Tiled GEMM, K=64. Output: half or f32 (final layer).
__global__ __launch_bounds__(256) void dense_kernel(
    const ushort* __restrict__ zin, const float* __restrict__ Wp,
    ushort* __restrict__ h_half, float* __restrict__ h_f32, int n) {
    __shared__ float Ws[DD * DD];
    __shared__ float xs[K_CHUNK][M_TILE + 4];
    for (int i = threadIdx.x; i < DD * DD; i += 256) Ws[i] = Wp[i];

    int t = threadIdx.x;
    int tm = t >> 4, tn = t & 15;
    int m0 = blockIdx.x * M_TILE;

    float acc[8][4];
#pragma unroll
    for (int mi = 0; mi < 8; ++mi)
#pragma unroll
        for (int j = 0; j < 4; ++j) acc[mi][j] = 0.f;

    for (int kk = 0; kk < DD; kk += K_CHUNK) {
        __syncthreads();
#pragma unroll
        for (int i = 0; i < 4; ++i) {
            int s = t + i * 256;
            int node = s >> 3;
            int cpos = (s & 7) * 4;
            int g = m0 + node;
            ushort4 v = make_ushort4(0, 0, 0, 0);
            if (g < n) v = *(const ushort4*)&zin[(size_t)g * DD + kk + cpos];
            xs[cpos + 0][node] = us2f(v.x);
            xs[cpos + 1][node] = us2f(v.y);
            xs[cpos + 2][node] = us2f(v.z);
            xs[cpos + 3][node] = us2f(v.w);
        }
        __syncthreads();
#pragma unroll
        for (int k = 0; k < K_CHUNK; ++k) {
            float4 wv = *(const float4*)&Ws[(kk + k) * DD + tn * 4];
            const float* xr = &xs[k][tm * 8];
            float4 xa = *(const float4*)xr;
            float4 xb = *(const float4*)(xr + 4);
            float xm[8] = {xa.x, xa.y, xa.z, xa.w, xb.x, xb.y, xb.z, xb.w};
            float wj[4] = {wv.x, wv.y, wv.z, wv.w};
#pragma unroll
            for (int mi = 0; mi < 8; ++mi)
#pragma unroll
                for (int j = 0; j < 4; ++j)
                    acc[mi][j] += xm[mi] * wj[j];
        }
    }
#pragma unroll
    for (int mi = 0; mi < 8; ++mi) {
        int node = m0 + tm * 8 + mi;
        if (node >= n) continue;
        float o0 = fmaxf(acc[mi][0], 0.f);
        float o1 = fmaxf(acc[mi][1], 0.f);
        float o2 = fmaxf(acc[mi][2], 0.f);
        float o3 = fmaxf(acc[mi][3], 0.f);
        if (h_f32) {
            *(float4*)&h_f32[(size_t)node * DD + tn * 4] =
                make_float4(o0, o1, o2, o3);
        } else {
            ushort4 o;
            o.x = f2h(o0); o.y = f2h(o1); o.z = f2h(o2); o.w = f2h(o3);
            *(ushort4*)&h_half[(size_t)node * DD + tn * 4] = o;
        }
    }
}

static inline size_t align256(size_t x) { return (x + 255) & ~(size_t)255; }

extern "C" void kernel_launch(void* const* d_in, const int* in_sizes, int n_in,
                              void* d_out, int out_size, void* d_ws, size_t ws_size,
                              hipStream_t stream) {
    const float* x      = (const float*)d_in[0];
    const int*   row    = (const int*)d_in[1];
    const int*   col    = (const int*)d_in[2];
    const float* ew     = (const float*)d_in[3];
    const float* w_lin  = (const float*)d_in[4];
    const float* b_lin  = (const float*)d_in[5];
    const float* conv_w = (const float*)d_in[6];
    float* out = (float*)d_out;

    const int N = in_sizes[0] / HH;          // 100000
    const int E = in_sizes[1];               // 1600000
    const int L = in_sizes[6] / (DD * DD);   // 4
    const int nb = (N + NPB - 1) / NPB;      // 782 buckets

    char* ws = (char*)d_ws;
    size_t off = 0;
    int* bcur = (int*)(ws + off);      off = align256(off + (size_t)NB_MAX * 4);
    uint2* pk = (uint2*)(ws + off);    off = align256(off + (size_t)nb * SLOT * 8);
    ushort* x0 = (ushort*)(ws + off);  off = align256(off + (size_t)N * DD * 2);
    ushort* hA = (ushort*)(ws + off);  off = align256(off + (size_t)N * DD * 2);
    ushort* hB = (ushort*)(ws + off);  off = align256(off + (size_t)N * DD * 2);
    ushort* zb = (ushort*)(ws + off);  off = align256(off + (size_t)N * DD * 2);
    float* Wp = (float*)(ws + off);    off = align256(off + (size_t)L * DD * DD * 4);
    (void)ws_size;

    const int mt = (N + M_TILE - 1) / M_TILE;

    // ---- edge prep: one-pass bucketed partition ----
    init_bcur<<<(nb + 255) / 256, 256, 0, stream>>>(bcur, nb);
    partition_kernel<<<PART_BLOCKS, 256, 0, stream>>>(row, col, ew, bcur, pk, E, nb);

    // ---- premixed layer weights ----
    int total = L * DD * DD;
    prep_w<<<(total + 255) / 256, 256, 0, stream>>>(conv_w, Wp, total);

    // ---- h0 = relu(x @ Wlin + b) -> x0, hA (half) ----
    lin0_kernel<<<mt, 256, 0, stream>>>(x, w_lin, b_lin, x0, hA, N);

    // ---- L layers: spmm -> dense; ping-pong hA/hB; final -> f32 out ----
    for (int l = 0; l < L; ++l) {
        const ushort* hin = (l % 2 == 0) ? hA : hB;
        ushort* hout      = (l % 2 == 0) ? hB : hA;
        spmm_kernel<<<nb, 512, 0, stream>>>(hin, x0, pk, bcur, zb, N);
        bool last = (l == L - 1);
        dense_kernel<<<mt, 256, 0, stream>>>(zb, Wp + (size_t)l * DD * DD,
                                             last ? nullptr : hout,
                                             last ? out : nullptr, N);
    }
}

// Round 7
// 444.714 us; speedup vs baseline: 6.4926x; 6.4926x over previous
//
#include <hip/hip_runtime.h>
#include <hip/hip_fp16.h>
#include <math.h>

// GCNII forward, fp16-compressed intermediates (round-4 pipeline restored).
//   h0 = relu(x @ Wlin + b)                       [lin0: tiled GEMM]
//   per layer l: z = 0.9*(A@h) + 0.1*x0           [gather: CSR, group-per-node]
//                h = relu(z @ W'_l)               [dense: tiled GEMM]
//   W'_l = (1-beta_l) I + beta_l W_l (premixed).
// CSR build: XCD-affine hist + 3-phase scan + XCD-affine scatter. Edge
// streams (row/col/ew) are read with NONTEMPORAL loads so they don't
// allocate in L2 and evict the partially-filled dirty cw lines (round-4
// counters: WRITE_SIZE 95MB for a 12.8MB cw buffer <- eviction-driven amp).
// Constants: N=100000, E=1600000, H=128, D=64, L=4.

#define DD 64
#define HH 128
#define SCAN_CHUNK 1024
#define M_TILE 128
#define K_CHUNK 32

__device__ inline ushort f2h(float f) { return __half_as_ushort(__float2half(f)); }
__device__ inline float us2f(ushort u) { return __half2float(__ushort_as_half(u)); }

__global__ __launch_bounds__(256) void zero_i32(int* p, int n) {
    int i = blockIdx.x * blockDim.x + threadIdx.x;
    if (i < n) p[i] = 0;
}

// Histogram, XCD-affine: group g counts only rows in its node range.
// Edge stream read nontemporally (no L2 allocation).
__global__ __launch_bounds__(256) void hist_kernel(const int* __restrict__ row,
                                                   int* __restrict__ cnt,
                                                   int E, int N) {
    int grp = blockIdx.x & 7;
    int bid = blockIdx.x >> 3;
    int nblk = gridDim.x >> 3;
    int lo = (int)((long long)N * grp / 8);
    int hi = (int)((long long)N * (grp + 1) / 8);
    for (int e = bid * blockDim.x + threadIdx.x; e < E; e += nblk * blockDim.x) {
        int r = __builtin_nontemporal_load(&row[e]);
        if (r >= lo && r < hi) atomicAdd(&cnt[r], 1);
    }
}

__global__ __launch_bounds__(256) void scanA(const int* __restrict__ cnt,
                                             int* __restrict__ bsum, int n) {
    __shared__ int s[256];
    int t = threadIdx.x;
    int base = blockIdx.x * SCAN_CHUNK + t * 4;
    int sum = 0;
#pragma unroll
    for (int i = 0; i < 4; ++i) {
        int idx = base + i;
        if (idx < n) sum += cnt[idx];
    }
    s[t] = sum;
    __syncthreads();
    for (int off = 128; off > 0; off >>= 1) {
        if (t < off) s[t] += s[t + off];
        __syncthreads();
    }
    if (t == 0) bsum[blockIdx.x] = s[0];
}

__global__ __launch_bounds__(64) void scanB(int* __restrict__ bsum, int nb,
                                            int* __restrict__ rowptr, int n) {
    int lane = threadIdx.x & 63;
    int i0 = 2 * lane, i1 = 2 * lane + 1;
    int a = (i0 < nb) ? bsum[i0] : 0;
    int b = (i1 < nb) ? bsum[i1] : 0;
    int s = a + b;
    for (int off = 1; off < 64; off <<= 1) {
        int t = __shfl_up(s, off);
        if (lane >= off) s += t;
    }
    int excl = s - (a + b);
    if (i0 < nb) bsum[i0] = excl;
    if (i1 < nb) bsum[i1] = excl + a;
    if (lane == 63) rowptr[n] = s;   // total == E
}

__global__ __launch_bounds__(256) void scanC(const int* __restrict__ cnt,
                                             const int* __restrict__ bsum,
                                             int* __restrict__ rowptr,
                                             int* __restrict__ fill, int n) {
    __shared__ int s[256];
    int t = threadIdx.x;
    int base = blockIdx.x * SCAN_CHUNK + t * 4;
    int v[4];
    int sum = 0;
#pragma unroll
    for (int i = 0; i < 4; ++i) {
        int idx = base + i;
        v[i] = (idx < n) ? cnt[idx] : 0;
        sum += v[i];
    }
    s[t] = sum;
    __syncthreads();
    for (int off = 1; off < 256; off <<= 1) {
        int x = (t >= off) ? s[t - off] : 0;
        __syncthreads();
        s[t] += x;
        __syncthreads();
    }
    int excl = (t == 0) ? 0 : s[t - 1];
    excl += bsum[blockIdx.x];
#pragma unroll
    for (int i = 0; i < 4; ++i) {
        int idx = base + i;
        if (idx < n) { rowptr[idx] = excl; fill[idx] = excl; excl += v[i]; }
    }
}

// Scatter {col, weight} records, XCD-affine by destination range.
// Edge streams nontemporal; cw stores regular (dirty lines should stay in
// L2 until the line is fully populated).
__global__ __launch_bounds__(256) void scatter_kernel(
    const int* __restrict__ row, const int* __restrict__ col,
    const float* __restrict__ ew, int* __restrict__ fill,
    int2* __restrict__ cw, int E, int N) {
    int grp = blockIdx.x & 7;
    int bid = blockIdx.x >> 3;
    int nblk = gridDim.x >> 3;
    int lo = (int)((long long)N * grp / 8);
    int hi = (int)((long long)N * (grp + 1) / 8);
    for (int e = bid * blockDim.x + threadIdx.x; e < E; e += nblk * blockDim.x) {
        int r = __builtin_nontemporal_load(&row[e]);
        if (r >= lo && r < hi) {
            int c = __builtin_nontemporal_load(&col[e]);
            float w = __builtin_nontemporal_load(&ew[e]);
            int pos = atomicAdd(&fill[r], 1);
            cw[pos] = make_int2(c, __float_as_int(w));
        }
    }
}

// W'_l = (1-beta_l) I + beta_l W_l, all L layers at once.
__global__ __launch_bounds__(256) void prep_w(const float* __restrict__ conv_w,
                                              float* __restrict__ Wp, int total) {
    int i = blockIdx.x * blockDim.x + threadIdx.x;
    if (i >= total) return;
    int l = i >> 12;
    int r = i & 4095;
    int d = r >> 6, j = r & 63;
    float beta = logf(0.5f / (float)(l + 1) + 1.0f);
    float v = beta * conv_w[i];
    if (d == j) v += 1.0f - beta;
    Wp[i] = v;
}

// h0 = relu(x @ Wlin + b). Register-tiled GEMM. Writes x0, h (half).
__global__ __launch_bounds__(256) void lin0_kernel(
    const float* __restrict__ x, const float* __restrict__ Wlin,
    const float* __restrict__ b, ushort* __restrict__ x0,
    ushort* __restrict__ h, int n) {
    __shared__ float Ws[HH * DD];              // 32 KB
    __shared__ float xs[K_CHUNK][M_TILE + 4];
    for (int i = threadIdx.x; i < HH * DD; i += 256) Ws[i] = Wlin[i];

    int t = threadIdx.x;
    int tm = t >> 4, tn = t & 15;
    int m0 = blockIdx.x * M_TILE;

    float4 bb = *(const float4*)&b[tn * 4];
    float acc[8][4];
#pragma unroll
    for (int mi = 0; mi < 8; ++mi) {
        acc[mi][0] = bb.x; acc[mi][1] = bb.y; acc[mi][2] = bb.z; acc[mi][3] = bb.w;
    }

    for (int kk = 0; kk < HH; kk += K_CHUNK) {
        __syncthreads();
#pragma unroll
        for (int i = 0; i < 4; ++i) {
            int s = t + i * 256;
            int node = s >> 3;
            int cpos = (s & 7) * 4;
            int g = m0 + node;
            float4 v = make_float4(0.f, 0.f, 0.f, 0.f);
            if (g < n) v = *(const float4*)&x[(size_t)g * HH + kk + cpos];
            xs[cpos + 0][node] = v.x;
            xs[cpos + 1][node] = v.y;
            xs[cpos + 2][node] = v.z;
            xs[cpos + 3][node] = v.w;
        }
        __syncthreads();
#pragma unroll
        for (int k = 0; k < K_CHUNK; ++k) {
            float4 wv = *(const float4*)&Ws[(kk + k) * DD + tn * 4];
            const float* xr = &xs[k][tm * 8];
            float4 xa = *(const float4*)xr;
            float4 xb = *(const float4*)(xr + 4);
            float xm[8] = {xa.x, xa.y, xa.z, xa.w, xb.x, xb.y, xb.z, xb.w};
            float wj[4] = {wv.x, wv.y, wv.z, wv.w};
#pragma unroll
            for (int mi = 0; mi < 8; ++mi)
#pragma unroll
                for (int j = 0; j < 4; ++j)
                    acc[mi][j] += xm[mi] * wj[j];
        }
    }
#pragma unroll
    for (int mi = 0; mi < 8; ++mi) {
        int node = m0 + tm * 8 + mi;
        if (node >= n) continue;
        ushort4 o;
        o.x = f2h(fmaxf(acc[mi][0], 0.f));
        o.y = f2h(fmaxf(acc[mi][1], 0.f));
        o.z = f2h(fmaxf(acc[mi][2], 0.f));
        o.w = f2h(fmaxf(acc[mi][3], 0.f));
        *(ushort4*)&x0[(size_t)node * DD + tn * 4] = o;
        *(ushort4*)&h[(size_t)node * DD + tn * 4] = o;
    }
}

// Gather/SpMM: z = 0.9*(A@h) + 0.1*x0 (half storage). Group-per-node:
// each 16-lane group owns one node (4 nodes/wave). Per group: stage up to
// 16 edge records (one coalesced 128B load) into its LDS slot, then 4x4
// unrolled gathers with 4 accumulator sets -> 16 independent chains/wave.
// Register accumulation only (no LDS atomics - round-6 lesson).
__global__ __launch_bounds__(256) void gather_kernel(
    const ushort* __restrict__ h_in, const ushort* __restrict__ x0,
    const int* __restrict__ rowptr, const int2* __restrict__ cw,
    ushort* __restrict__ z, int n) {
    __shared__ int2 es[4][64];
    int wave = threadIdx.x >> 6, lane = threadIdx.x & 63;
    int grp = lane >> 4, sub = lane & 15;
    int2* slot = &es[wave][grp * 16];

    for (int nb = (blockIdx.x * 4 + wave) * 4; nb < n; nb += gridDim.x * 16) {
        int node = nb + grp;
        bool nvalid = node < n;
        int nn = nvalid ? node : (n - 1);
        int beg = rowptr[nn];
        int end = nvalid ? rowptr[nn + 1] : beg;
        uint2 x0v = *(const uint2*)&x0[(size_t)nn * DD + sub * 4];
        float acc[4][4];
#pragma unroll
        for (int c = 0; c < 4; ++c)
#pragma unroll
            for (int f = 0; f < 4; ++f) acc[c][f] = 0.f;

        for (int base = beg; base < end; base += 16) {
            int m = end - base;
            if (m > 16) m = 16;
            if (sub < m) slot[sub] = cw[base + sub];
            // same-wave LDS write->read; compiler orders via lgkmcnt
#pragma unroll
            for (int j = 0; j < 4; ++j) {
#pragma unroll
                for (int c = 0; c < 4; ++c) {
                    int idx = j * 4 + c;
                    bool v = idx < m;
                    int2 r = slot[v ? idx : 0];
                    float w = v ? __int_as_float(r.y) : 0.f;
                    uint2 hv = *(const uint2*)&h_in[(size_t)r.x * DD + sub * 4];
                    acc[c][0] += w * us2f((ushort)(hv.x & 0xffff));
                    acc[c][1] += w * us2f((ushort)(hv.x >> 16));
                    acc[c][2] += w * us2f((ushort)(hv.y & 0xffff));
                    acc[c][3] += w * us2f((ushort)(hv.y >> 16));
                }
            }
        }
        float f0 = (acc[0][0] + acc[1][0]) + (acc[2][0] + acc[3][0]);
        float f1 = (acc[0][1] + acc[1][1]) + (acc[2][1] + acc[3][1]);
        float f2 = (acc[0][2] + acc[1][2]) + (acc[2][2] + acc[3][2]);
        float f3 = (acc[0][3] + acc[1][3]) + (acc[2][3] + acc[3][3]);
        if (nvalid) {
            float z0 = 0.9f * f0 + 0.1f * us2f((ushort)(x0v.x & 0xffff));
            float z1 = 0.9f * f1 + 0.1f * us2f((ushort)(x0v.x >> 16));
            float z2 = 0.9f * f2 + 0.1f * us2f((ushort)(x0v.y & 0xffff));
            float z3 = 0.9f * f3 + 0.1f * us2f((ushort)(x0v.y >> 16));
            uint zlo = (uint)f2h(z0) | ((uint)f2h(z1) << 16);
            uint zhi = (uint)f2h(z2) | ((uint)f2h(z3) << 16);
            *(uint2*)&z[(size_t)node * DD + sub * 4] = make_uint2(zlo, zhi);
        }
    }
}

// h = relu(z @ W'). Tiled GEMM, K=64. Output: half or f32 (final layer).
__global__ __launch_bounds__(256) void dense_kernel(
    const ushort* __restrict__ zin, const float* __restrict__ Wp,
    ushort* __restrict__ h_half, float* __restrict__ h_f32, int n) {
    __shared__ float Ws[DD * DD];
    __shared__ float xs[K_CHUNK][M_TILE + 4];
    for (int i = threadIdx.x; i < DD * DD; i += 256) Ws[i] = Wp[i];

    int t = threadIdx.x;
    int tm = t >> 4, tn = t & 15;
    int m0 = blockIdx.x * M_TILE;

    float acc[8][4];
#pragma unroll
    for (int mi = 0; mi < 8; ++mi)
#pragma unroll
        for (int j = 0; j < 4; ++j) acc[mi][j] = 0.f;

    for (int kk = 0; kk < DD; kk += K_CHUNK) {
        __syncthreads();
#pragma unroll
        for (int i = 0; i < 4; ++i) {
            int s = t + i * 256;
            int node = s >> 3;
            int cpos = (s & 7) * 4;
            int g = m0 + node;
            ushort4 v = make_ushort4(0, 0, 0, 0);
            if (g < n) v = *(const ushort4*)&zin[(size_t)g * DD + kk + cpos];
            xs[cpos + 0][node] = us2f(v.x);
            xs[cpos + 1][node] = us2f(v.y);
            xs[cpos + 2][node] = us2f(v.z);
            xs[cpos + 3][node] = us2f(v.w);
        }
        __syncthreads();
#pragma unroll
        for (int k = 0; k < K_CHUNK; ++k) {
            float4 wv = *(const float4*)&Ws[(kk + k) * DD + tn * 4];
            const float* xr = &xs[k][tm * 8];
            float4 xa = *(const float4*)xr;
            float4 xb = *(const float4*)(xr + 4);
            float xm[8] = {xa.x, xa.y, xa.z, xa.w, xb.x, xb.y, xb.z, xb.w};
            float wj[4] = {wv.x, wv.y, wv.z, wv.w};
#pragma unroll
            for (int mi = 0; mi < 8; ++mi)
#pragma unroll
                for (int j = 0; j < 4; ++j)
                    acc[mi][j] += xm[mi] * wj[j];
        }
    }
#pragma unroll
    for (int mi = 0; mi < 8; ++mi) {
        int node = m0 + tm * 8 + mi;
        if (node >= n) continue;
        float o0 = fmaxf(acc[mi][0], 0.f);
        float o1 = fmaxf(acc[mi][1], 0.f);
        float o2 = fmaxf(acc[mi][2], 0.f);
        float o3 = fmaxf(acc[mi][3], 0.f);
        if (h_f32) {
            *(float4*)&h_f32[(size_t)node * DD + tn * 4] =
                make_float4(o0, o1, o2, o3);
        } else {
            ushort4 o;
            o.x = f2h(o0); o.y = f2h(o1); o.z = f2h(o2); o.w = f2h(o3);
            *(ushort4*)&h_half[(size_t)node * DD + tn * 4] = o;
        }
    }
}

static inline size_t align256(size_t x) { return (x + 255) & ~(size_t)255; }

extern "C" void kernel_launch(void* const* d_in, const int* in_sizes, int n_in,
                              void* d_out, int out_size, void* d_ws, size_t ws_size,
                              hipStream_t stream) {
    const float* x      = (const float*)d_in[0];
    const int*   row    = (const int*)d_in[1];
    const int*   col    = (const int*)d_in[2];
    const float* ew     = (const float*)d_in[3];
    const float* w_lin  = (const float*)d_in[4];
    const float* b_lin  = (const float*)d_in[5];
    const float* conv_w = (const float*)d_in[6];
    float* out = (float*)d_out;

    const int N = in_sizes[0] / HH;          // 100000
    const int E = in_sizes[1];               // 1600000
    const int L = in_sizes[6] / (DD * DD);   // 4

    char* ws = (char*)d_ws;
    size_t off = 0;
    int* cnt = (int*)(ws + off);       off = align256(off + (size_t)N * 4);
    int* rowptr = (int*)(ws + off);    off = align256(off + (size_t)(N + 1) * 4);
    int* fill = (int*)(ws + off);      off = align256(off + (size_t)N * 4);
    int* bsum = (int*)(ws + off);      off = align256(off + 1024 * 4);
    int2* cw = (int2*)(ws + off);      off = align256(off + (size_t)E * 8);
    ushort* x0 = (ushort*)(ws + off);  off = align256(off + (size_t)N * DD * 2);
    ushort* hA = (ushort*)(ws + off);  off = align256(off + (size_t)N * DD * 2);
    ushort* hB = (ushort*)(ws + off);  off = align256(off + (size_t)N * DD * 2);
    ushort* zb = (ushort*)(ws + off);  off = align256(off + (size_t)N * DD * 2);
    float* Wp = (float*)(ws + off);    off = align256(off + (size_t)L * DD * DD * 4);
    (void)ws_size;

    const int nb = (N + SCAN_CHUNK - 1) / SCAN_CHUNK;
    const int mt = (N + M_TILE - 1) / M_TILE;

    // ---- CSR build (XCD-affine hist + scatter, nt edge streams) ----
    zero_i32<<<(N + 255) / 256, 256, 0, stream>>>(cnt, N);
    hist_kernel<<<2048, 256, 0, stream>>>(row, cnt, E, N);
    scanA<<<nb, 256, 0, stream>>>(cnt, bsum, N);
    scanB<<<1, 64, 0, stream>>>(bsum, nb, rowptr, N);
    scanC<<<nb, 256, 0, stream>>>(cnt, bsum, rowptr, fill, N);
    scatter_kernel<<<2048, 256, 0, stream>>>(row, col, ew, fill, cw, E, N);

    // ---- premixed layer weights ----
    int total = L * DD * DD;
    prep_w<<<(total + 255) / 256, 256, 0, stream>>>(conv_w, Wp, total);

    // ---- h0 = relu(x @ Wlin + b) -> x0, hA (half) ----
    lin0_kernel<<<mt, 256, 0, stream>>>(x, w_lin, b_lin, x0, hA, N);

    // ---- L layers: gather -> dense; ping-pong hA/hB; final -> f32 out ----
    for (int l = 0; l < L; ++l) {
        const ushort* hin = (l % 2 == 0) ? hA : hB;
        ushort* hout      = (l % 2 == 0) ? hB : hA;
        gather_kernel<<<2048, 256, 0, stream>>>(hin, x0, rowptr, cw, zb, N);
        bool last = (l == L - 1);
        dense_kernel<<<mt, 256, 0, stream>>>(zb, Wp + (size_t)l * DD * DD,
                                             last ? nullptr : hout,
                                             last ? out : nullptr, N);
    }
}

// Round 8
// 377.822 us; speedup vs baseline: 7.6420x; 1.1770x over previous
//
#include <hip/hip_runtime.h>
#include <hip/hip_fp16.h>
#include <math.h>

// GCNII forward, fp16-compressed intermediates.
//   h0 = relu(x @ Wlin + b)                       [lin0: tiled GEMM]
//   per layer l: z = 0.9*(A@h) + 0.1*x0           [gather: CSR, group-per-node]
//                h = relu(z @ W'_l)               [dense: tiled GEMM]
//   W'_l = (1-beta_l) I + beta_l W_l (premixed).
// CSR build = bucketed counting sort with NO fine-grained random global
// stores (rounds 4/5/7 showed 6x write amp for random 8B stores):
//   partition: per-block LDS count -> per-(block,bucket) reserved runs of
//              ~16 contiguous records (line-merged writes, amp <=2x)
//   sort:      block = 128-node bucket; sequential record reads, LDS hist +
//              scan, placement into the bucket's 16KB CSR window (L2-hot,
//              lines fully covered -> amp ~1). rowptr2 = {beg,end} pairs,
//              bucket-relative bases (no global scan).
// Constants: N=100000, E=1600000, H=128, D=64, L=4.

#define DD 64
#define HH 128
#define M_TILE 128
#define K_CHUNK 32
#define NPB 128            // nodes per bucket (bucket = node>>7)
#define SLOT 2560          // record slots per bucket (mean ~2046, +11 sigma)
#define NBUK_MAX 1024
#define PART_BLOCKS 128

__device__ inline ushort f2h(float f) { return __half_as_ushort(__float2half(f)); }
__device__ inline float us2f(ushort u) { return __half2float(__ushort_as_half(u)); }

__global__ __launch_bounds__(256) void init_bcur(int* bcur, int nbuk) {
    int i = blockIdx.x * blockDim.x + threadIdx.x;
    if (i < nbuk) bcur[i] = i * SLOT;
}

// One-pass partition into bucket slots. Record: {row:17 | col_lo15:15},
// {col_hi2:2 | w_fp16:16<<2}. Per-block LDS count, one cursor reservation
// per (block,bucket), then bucket-local sequential runs (~16 records).
__global__ __launch_bounds__(256) void partition_kernel(
    const int* __restrict__ row, const int* __restrict__ col,
    const float* __restrict__ ew, int* __restrict__ bcur,
    uint2* __restrict__ pk, int E, int nbuk) {
    __shared__ int cnt[NBUK_MAX], base[NBUK_MAX], rc[NBUK_MAX];
    int t = threadIdx.x;
    for (int i = t; i < nbuk; i += 256) { cnt[i] = 0; rc[i] = 0; }
    __syncthreads();
    int chunk = (E + gridDim.x - 1) / gridDim.x;
    int s0 = blockIdx.x * chunk;
    int s1 = min(s0 + chunk, E);
    for (int e = s0 + t; e < s1; e += 256)
        atomicAdd(&cnt[__builtin_nontemporal_load(&row[e]) >> 7], 1);
    __syncthreads();
    for (int i = t; i < nbuk; i += 256)
        if (cnt[i] > 0) base[i] = atomicAdd(&bcur[i], cnt[i]);
    __syncthreads();
    for (int e = s0 + t; e < s1; e += 256) {
        int r = __builtin_nontemporal_load(&row[e]);
        int c = __builtin_nontemporal_load(&col[e]);
        ushort wh = f2h(__builtin_nontemporal_load(&ew[e]));
        int b = r >> 7;
        int pos = base[b] + atomicAdd(&rc[b], 1);
        if (pos < (b + 1) * SLOT)   // defensive (SLOT is +11 sigma)
            pk[pos] = make_uint2((uint)r | (((uint)c & 0x7fffu) << 17),
                                 ((uint)c >> 15) | ((uint)wh << 2));
    }
}

// Per-bucket counting sort -> CSR segment at cw[b*SLOT ..] + rowptr2 pairs.
__global__ __launch_bounds__(256) void sort_kernel(
    const uint2* __restrict__ pk, const int* __restrict__ bcur,
    int2* __restrict__ cw, int2* __restrict__ rowptr2, int n) {
    __shared__ int hist[NPB], scan[NPB], rc[NPB];
    int b = blockIdx.x, lo = b << 7;
    int cnt = min(bcur[b] - b * SLOT, SLOT);
    const uint2* rec = pk + (size_t)b * SLOT;
    int t = threadIdx.x;
    if (t < NPB) { hist[t] = 0; rc[t] = 0; }
    __syncthreads();
    for (int i = t; i < cnt; i += 256)
        atomicAdd(&hist[(rec[i].x & 0x1ffffu) - lo], 1);
    __syncthreads();
    if (t < NPB) scan[t] = hist[t];
    __syncthreads();
    for (int off = 1; off < NPB; off <<= 1) {       // inclusive scan
        int v = (t < NPB && t >= off) ? scan[t - off] : 0;
        __syncthreads();
        if (t < NPB) scan[t] += v;
        __syncthreads();
    }
    if (t < NPB && lo + t < n) {
        int beg = b * SLOT + scan[t] - hist[t];     // exclusive base
        rowptr2[lo + t] = make_int2(beg, beg + hist[t]);
    }
    for (int i = t; i < cnt; i += 256) {
        uint2 r2 = rec[i];
        int nl = (int)(r2.x & 0x1ffffu) - lo;
        int c = (int)((r2.x >> 17) | ((r2.y & 3u) << 15));
        float w = us2f((ushort)((r2.y >> 2) & 0xffffu));
        int pos = (scan[nl] - hist[nl]) + atomicAdd(&rc[nl], 1);
        cw[b * SLOT + pos] = make_int2(c, __float_as_int(w));
    }
}

// W'_l = (1-beta_l) I + beta_l W_l, all L layers at once.
__global__ __launch_bounds__(256) void prep_w(const float* __restrict__ conv_w,
                                              float* __restrict__ Wp, int total) {
    int i = blockIdx.x * blockDim.x + threadIdx.x;
    if (i >= total) return;
    int l = i >> 12;
    int r = i & 4095;
    int d = r >> 6, j = r & 63;
    float beta = logf(0.5f / (float)(l + 1) + 1.0f);
    float v = beta * conv_w[i];
    if (d == j) v += 1.0f - beta;
    Wp[i] = v;
}

// h0 = relu(x @ Wlin + b). Register-tiled GEMM. Writes x0, h (half).
__global__ __launch_bounds__(256) void lin0_kernel(
    const float* __restrict__ x, const float* __restrict__ Wlin,
    const float* __restrict__ b, ushort* __restrict__ x0,
    ushort* __restrict__ h, int n) {
    __shared__ float Ws[HH * DD];              // 32 KB
    __shared__ float xs[K_CHUNK][M_TILE + 4];
    for (int i = threadIdx.x; i < HH * DD; i += 256) Ws[i] = Wlin[i];

    int t = threadIdx.x;
    int tm = t >> 4, tn = t & 15;
    int m0 = blockIdx.x * M_TILE;

    float4 bb = *(const float4*)&b[tn * 4];
    float acc[8][4];
#pragma unroll
    for (int mi = 0; mi < 8; ++mi) {
        acc[mi][0] = bb.x; acc[mi][1] = bb.y; acc[mi][2] = bb.z; acc[mi][3] = bb.w;
    }

    for (int kk = 0; kk < HH; kk += K_CHUNK) {
        __syncthreads();
#pragma unroll
        for (int i = 0; i < 4; ++i) {
            int s = t + i * 256;
            int node = s >> 3;
            int cpos = (s & 7) * 4;
            int g = m0 + node;
            float4 v = make_float4(0.f, 0.f, 0.f, 0.f);
            if (g < n) v = *(const float4*)&x[(size_t)g * HH + kk + cpos];
            xs[cpos + 0][node] = v.x;
            xs[cpos + 1][node] = v.y;
            xs[cpos + 2][node] = v.z;
            xs[cpos + 3][node] = v.w;
        }
        __syncthreads();
#pragma unroll
        for (int k = 0; k < K_CHUNK; ++k) {
            float4 wv = *(const float4*)&Ws[(kk + k) * DD + tn * 4];
            const float* xr = &xs[k][tm * 8];
            float4 xa = *(const float4*)xr;
            float4 xb = *(const float4*)(xr + 4);
            float xm[8] = {xa.x, xa.y, xa.z, xa.w, xb.x, xb.y, xb.z, xb.w};
            float wj[4] = {wv.x, wv.y, wv.z, wv.w};
#pragma unroll
            for (int mi = 0; mi < 8; ++mi)
#pragma unroll
                for (int j = 0; j < 4; ++j)
                    acc[mi][j] += xm[mi] * wj[j];
        }
    }
#pragma unroll
    for (int mi = 0; mi < 8; ++mi) {
        int node = m0 + tm * 8 + mi;
        if (node >= n) continue;
        ushort4 o;
        o.x = f2h(fmaxf(acc[mi][0], 0.f));
        o.y = f2h(fmaxf(acc[mi][1], 0.f));
        o.z = f2h(fmaxf(acc[mi][2], 0.f));
        o.w = f2h(fmaxf(acc[mi][3], 0.f));
        *(ushort4*)&x0[(size_t)node * DD + tn * 4] = o;
        *(ushort4*)&h[(size_t)node * DD + tn * 4] = o;
    }
}

// Gather/SpMM: z = 0.9*(A@h) + 0.1*x0 (half storage). Group-per-node:
// each 16-lane group owns one node (4 nodes/wave). Register accumulation
// only (round-6 lesson: no LDS atomics on the per-edge path).
__global__ __launch_bounds__(256) void gather_kernel(
    const ushort* __restrict__ h_in, const ushort* __restrict__ x0,
    const int2* __restrict__ rowptr2, const int2* __restrict__ cw,
    ushort* __restrict__ z, int n) {
    __shared__ int2 es[4][64];
    int wave = threadIdx.x >> 6, lane = threadIdx.x & 63;
    int grp = lane >> 4, sub = lane & 15;
    int2* slot = &es[wave][grp * 16];

    for (int nb = (blockIdx.x * 4 + wave) * 4; nb < n; nb += gridDim.x * 16) {
        int node = nb + grp;
        bool nvalid = node < n;
        int nn = nvalid ? node : (n - 1);
        int2 rp = rowptr2[nn];
        int beg = rp.x;
        int end = nvalid ? rp.y : beg;
        uint2 x0v = *(const uint2*)&x0[(size_t)nn * DD + sub * 4];
        float acc[4][4];
#pragma unroll
        for (int c = 0; c < 4; ++c)
#pragma unroll
            for (int f = 0; f < 4; ++f) acc[c][f] = 0.f;

        for (int base = beg; base < end; base += 16) {
            int m = end - base;
            if (m > 16) m = 16;
            if (sub < m) slot[sub] = cw[base + sub];
            // same-wave LDS write->read; compiler orders via lgkmcnt
#pragma unroll
            for (int j = 0; j < 4; ++j) {
#pragma unroll
                for (int c = 0; c < 4; ++c) {
                    int idx = j * 4 + c;
                    bool v = idx < m;
                    int2 r = slot[v ? idx : 0];
                    float w = v ? __int_as_float(r.y) : 0.f;
                    uint2 hv = *(const uint2*)&h_in[(size_t)r.x * DD + sub * 4];
                    acc[c][0] += w * us2f((ushort)(hv.x & 0xffff));
                    acc[c][1] += w * us2f((ushort)(hv.x >> 16));
                    acc[c][2] += w * us2f((ushort)(hv.y & 0xffff));
                    acc[c][3] += w * us2f((ushort)(hv.y >> 16));
                }
            }
        }
        float f0 = (acc[0][0] + acc[1][0]) + (acc[2][0] + acc[3][0]);
        float f1 = (acc[0][1] + acc[1][1]) + (acc[2][1] + acc[3][1]);
        float f2 = (acc[0][2] + acc[1][2]) + (acc[2][2] + acc[3][2]);
        float f3 = (acc[0][3] + acc[1][3]) + (acc[2][3] + acc[3][3]);
        if (nvalid) {
            float z0 = 0.9f * f0 + 0.1f * us2f((ushort)(x0v.x & 0xffff));
            float z1 = 0.9f * f1 + 0.1f * us2f((ushort)(x0v.x >> 16));
            float z2 = 0.9f * f2 + 0.1f * us2f((ushort)(x0v.y & 0xffff));
            float z3 = 0.9f * f3 + 0.1f * us2f((ushort)(x0v.y >> 16));
            uint zlo = (uint)f2h(z0) | ((uint)f2h(z1) << 16);
            uint zhi = (uint)f2h(z2) | ((uint)f2h(z3) << 16);
            *(uint2*)&z[(size_t)node * DD + sub * 4] = make_uint2(zlo, zhi);
        }
    }
}

// h = relu(z @ W'). Tiled GEMM, K=64. Output: half or f32 (final layer).
__global__ __launch_bounds__(256) void dense_kernel(
    const ushort* __restrict__ zin, const float* __restrict__ Wp,
    ushort* __restrict__ h_half, float* __restrict__ h_f32, int n) {
    __shared__ float Ws[DD * DD];
    __shared__ float xs[K_CHUNK][M_TILE + 4];
    for (int i = threadIdx.x; i < DD * DD; i += 256) Ws[i] = Wp[i];

    int t = threadIdx.x;
    int tm = t >> 4, tn = t & 15;
    int m0 = blockIdx.x * M_TILE;

    float acc[8][4];
#pragma unroll
    for (int mi = 0; mi < 8; ++mi)
#pragma unroll
        for (int j = 0; j < 4; ++j) acc[mi][j] = 0.f;

    for (int kk = 0; kk < DD; kk += K_CHUNK) {
        __syncthreads();
#pragma unroll
        for (int i = 0; i < 4; ++i) {
            int s = t + i * 256;
            int node = s >> 3;
            int cpos = (s & 7) * 4;
            int g = m0 + node;
            ushort4 v = make_ushort4(0, 0, 0, 0);
            if (g < n) v = *(const ushort4*)&zin[(size_t)g * DD + kk + cpos];
            xs[cpos + 0][node] = us2f(v.x);
            xs[cpos + 1][node] = us2f(v.y);
            xs[cpos + 2][node] = us2f(v.z);
            xs[cpos + 3][node] = us2f(v.w);
        }
        __syncthreads();
#pragma unroll
        for (int k = 0; k < K_CHUNK; ++k) {
            float4 wv = *(const float4*)&Ws[(kk + k) * DD + tn * 4];
            const float* xr = &xs[k][tm * 8];
            float4 xa = *(const float4*)xr;
            float4 xb = *(const float4*)(xr + 4);
            float xm[8] = {xa.x, xa.y, xa.z, xa.w, xb.x, xb.y, xb.z, xb.w};
            float wj[4] = {wv.x, wv.y, wv.z, wv.w};
#pragma unroll
            for (int mi = 0; mi < 8; ++mi)
#pragma unroll
                for (int j = 0; j < 4; ++j)
                    acc[mi][j] += xm[mi] * wj[j];
        }
    }
#pragma unroll
    for (int mi = 0; mi < 8; ++mi) {
        int node = m0 + tm * 8 + mi;
        if (node >= n) continue;
        float o0 = fmaxf(acc[mi][0], 0.f);
        float o1 = fmaxf(acc[mi][1], 0.f);
        float o2 = fmaxf(acc[mi][2], 0.f);
        float o3 = fmaxf(acc[mi][3], 0.f);
        if (h_f32) {
            *(float4*)&h_f32[(size_t)node * DD + tn * 4] =
                make_float4(o0, o1, o2, o3);
        } else {
            ushort4 o;
            o.x = f2h(o0); o.y = f2h(o1); o.z = f2h(o2); o.w = f2h(o3);
            *(ushort4*)&h_half[(size_t)node * DD + tn * 4] = o;
        }
    }
}

static inline size_t align256(size_t x) { return (x + 255) & ~(size_t)255; }

extern "C" void kernel_launch(void* const* d_in, const int* in_sizes, int n_in,
                              void* d_out, int out_size, void* d_ws, size_t ws_size,
                              hipStream_t stream) {
    const float* x      = (const float*)d_in[0];
    const int*   row    = (const int*)d_in[1];
    const int*   col    = (const int*)d_in[2];
    const float* ew     = (const float*)d_in[3];
    const float* w_lin  = (const float*)d_in[4];
    const float* b_lin  = (const float*)d_in[5];
    const float* conv_w = (const float*)d_in[6];
    float* out = (float*)d_out;

    const int N = in_sizes[0] / HH;          // 100000
    const int E = in_sizes[1];               // 1600000
    const int L = in_sizes[6] / (DD * DD);   // 4
    const int nbuk = (N + NPB - 1) / NPB;    // 782

    char* ws = (char*)d_ws;
    size_t off = 0;
    int* bcur = (int*)(ws + off);        off = align256(off + (size_t)NBUK_MAX * 4);
    uint2* pk = (uint2*)(ws + off);      off = align256(off + (size_t)nbuk * SLOT * 8);
    int2* cw = (int2*)(ws + off);        off = align256(off + (size_t)nbuk * SLOT * 8);
    int2* rowptr2 = (int2*)(ws + off);   off = align256(off + (size_t)N * 8);
    ushort* x0 = (ushort*)(ws + off);    off = align256(off + (size_t)N * DD * 2);
    ushort* hA = (ushort*)(ws + off);    off = align256(off + (size_t)N * DD * 2);
    ushort* hB = (ushort*)(ws + off);    off = align256(off + (size_t)N * DD * 2);
    ushort* zb = (ushort*)(ws + off);    off = align256(off + (size_t)N * DD * 2);
    float* Wp = (float*)(ws + off);      off = align256(off + (size_t)L * DD * DD * 4);
    (void)ws_size;

    const int mt = (N + M_TILE - 1) / M_TILE;

    // ---- CSR build: bucketed counting sort (no random sub-line stores) ----
    init_bcur<<<(nbuk + 255) / 256, 256, 0, stream>>>(bcur, nbuk);
    partition_kernel<<<PART_BLOCKS, 256, 0, stream>>>(row, col, ew, bcur, pk, E, nbuk);
    sort_kernel<<<nbuk, 256, 0, stream>>>(pk, bcur, cw, rowptr2, N);

    // ---- premixed layer weights ----
    int total = L * DD * DD;
    prep_w<<<(total + 255) / 256, 256, 0, stream>>>(conv_w, Wp, total);

    // ---- h0 = relu(x @ Wlin + b) -> x0, hA (half) ----
    lin0_kernel<<<mt, 256, 0, stream>>>(x, w_lin, b_lin, x0, hA, N);

    // ---- L layers: gather -> dense; ping-pong hA/hB; final -> f32 out ----
    for (int l = 0; l < L; ++l) {
        const ushort* hin = (l % 2 == 0) ? hA : hB;
        ushort* hout      = (l % 2 == 0) ? hB : hA;
        gather_kernel<<<2048, 256, 0, stream>>>(hin, x0, rowptr2, cw, zb, N);
        bool last = (l == L - 1);
        dense_kernel<<<mt, 256, 0, stream>>>(zb, Wp + (size_t)l * DD * DD,
                                             last ? nullptr : hout,
                                             last ? out : nullptr, N);
    }
}

// Round 9
// 341.420 us; speedup vs baseline: 8.4568x; 1.1066x over previous
//
#include <hip/hip_runtime.h>
#include <hip/hip_fp16.h>
#include <math.h>

// GCNII forward, fp16-compressed intermediates.
//   h0 = relu(x @ Wlin + b)                       [lin0: tiled GEMM]
//   per layer l: z = 0.9*(A@h) + 0.1*x0           [gather: CSR, group-per-node]
//                h = relu(z @ W'_l)               [dense: tiled GEMM]
//   W'_l = (1-beta_l) I + beta_l W_l (premixed).
// CSR build = bucketed counting sort with NO fine-grained random global
// stores. partition: 256 blocks x 1024 threads (round-8 fix: 128x256 gave
// 4.5% occupancy -> latency-exposed at 75us). Per-(block,bucket) runs ~8
// records (64B) keep write merging. sort: block = 128-node bucket, CSR
// window L2-hot.
// Constants: N=100000, E=1600000, H=128, D=64, L=4.

#define DD 64
#define HH 128
#define M_TILE 128
#define K_CHUNK 32
#define NPB 128            // nodes per bucket (bucket = node>>7)
#define SLOT 2560          // record slots per bucket (mean ~2046, +11 sigma)
#define NBUK_MAX 1024
#define PART_BLOCKS 256
#define PART_THREADS 1024

__device__ inline ushort f2h(float f) { return __half_as_ushort(__float2half(f)); }
__device__ inline float us2f(ushort u) { return __half2float(__ushort_as_half(u)); }

__global__ __launch_bounds__(256) void init_bcur(int* bcur, int nbuk) {
    int i = blockIdx.x * blockDim.x + threadIdx.x;
    if (i < nbuk) bcur[i] = i * SLOT;
}

// One-pass partition into bucket slots. Record: {row:17 | col_lo15:15},
// {col_hi2:2 | w_fp16:16<<2}. Per-block LDS count, one cursor reservation
// per (block,bucket), then bucket-local sequential runs (~8 records).
__global__ __launch_bounds__(PART_THREADS) void partition_kernel(
    const int* __restrict__ row, const int* __restrict__ col,
    const float* __restrict__ ew, int* __restrict__ bcur,
    uint2* __restrict__ pk, int E, int nbuk) {
    __shared__ int cnt[NBUK_MAX], base[NBUK_MAX], rc[NBUK_MAX];
    int t = threadIdx.x;
    for (int i = t; i < nbuk; i += PART_THREADS) { cnt[i] = 0; rc[i] = 0; }
    __syncthreads();
    int chunk = (E + gridDim.x - 1) / gridDim.x;
    int s0 = blockIdx.x * chunk;
    int s1 = min(s0 + chunk, E);
    for (int e = s0 + t; e < s1; e += PART_THREADS)
        atomicAdd(&cnt[__builtin_nontemporal_load(&row[e]) >> 7], 1);
    __syncthreads();
    for (int i = t; i < nbuk; i += PART_THREADS)
        if (cnt[i] > 0) base[i] = atomicAdd(&bcur[i], cnt[i]);
    __syncthreads();
    for (int e = s0 + t; e < s1; e += PART_THREADS) {
        int r = __builtin_nontemporal_load(&row[e]);
        int c = __builtin_nontemporal_load(&col[e]);
        ushort wh = f2h(__builtin_nontemporal_load(&ew[e]));
        int b = r >> 7;
        int pos = base[b] + atomicAdd(&rc[b], 1);
        if (pos < (b + 1) * SLOT)   // defensive (SLOT is +11 sigma)
            pk[pos] = make_uint2((uint)r | (((uint)c & 0x7fffu) << 17),
                                 ((uint)c >> 15) | ((uint)wh << 2));
    }
}

// Per-bucket counting sort -> CSR segment at cw[b*SLOT ..] + rowptr2 pairs.
__global__ __launch_bounds__(256) void sort_kernel(
    const uint2* __restrict__ pk, const int* __restrict__ bcur,
    int2* __restrict__ cw, int2* __restrict__ rowptr2, int n) {
    __shared__ int hist[NPB], scan[NPB], rc[NPB];
    int b = blockIdx.x, lo = b << 7;
    int cnt = min(bcur[b] - b * SLOT, SLOT);
    const uint2* rec = pk + (size_t)b * SLOT;
    int t = threadIdx.x;
    if (t < NPB) { hist[t] = 0; rc[t] = 0; }
    __syncthreads();
    for (int i = t; i < cnt; i += 256)
        atomicAdd(&hist[(rec[i].x & 0x1ffffu) - lo], 1);
    __syncthreads();
    if (t < NPB) scan[t] = hist[t];
    __syncthreads();
    for (int off = 1; off < NPB; off <<= 1) {       // inclusive scan
        int v = (t < NPB && t >= off) ? scan[t - off] : 0;
        __syncthreads();
        if (t < NPB) scan[t] += v;
        __syncthreads();
    }
    if (t < NPB && lo + t < n) {
        int beg = b * SLOT + scan[t] - hist[t];     // exclusive base
        rowptr2[lo + t] = make_int2(beg, beg + hist[t]);
    }
    for (int i = t; i < cnt; i += 256) {
        uint2 r2 = rec[i];
        int nl = (int)(r2.x & 0x1ffffu) - lo;
        int c = (int)((r2.x >> 17) | ((r2.y & 3u) << 15));
        float w = us2f((ushort)((r2.y >> 2) & 0xffffu));
        int pos = (scan[nl] - hist[nl]) + atomicAdd(&rc[nl], 1);
        cw[b * SLOT + pos] = make_int2(c, __float_as_int(w));
    }
}

// W'_l = (1-beta_l) I + beta_l W_l, all L layers at once.
__global__ __launch_bounds__(256) void prep_w(const float* __restrict__ conv_w,
                                              float* __restrict__ Wp, int total) {
    int i = blockIdx.x * blockDim.x + threadIdx.x;
    if (i >= total) return;
    int l = i >> 12;
    int r = i & 4095;
    int d = r >> 6, j = r & 63;
    float beta = logf(0.5f / (float)(l + 1) + 1.0f);
    float v = beta * conv_w[i];
    if (d == j) v += 1.0f - beta;
    Wp[i] = v;
}

// h0 = relu(x @ Wlin + b). Register-tiled GEMM. Writes x0, h (half).
__global__ __launch_bounds__(256) void lin0_kernel(
    const float* __restrict__ x, const float* __restrict__ Wlin,
    const float* __restrict__ b, ushort* __restrict__ x0,
    ushort* __restrict__ h, int n) {
    __shared__ float Ws[HH * DD];              // 32 KB
    __shared__ float xs[K_CHUNK][M_TILE + 4];
    for (int i = threadIdx.x; i < HH * DD; i += 256) Ws[i] = Wlin[i];

    int t = threadIdx.x;
    int tm = t >> 4, tn = t & 15;
    int m0 = blockIdx.x * M_TILE;

    float4 bb = *(const float4*)&b[tn * 4];
    float acc[8][4];
#pragma unroll
    for (int mi = 0; mi < 8; ++mi) {
        acc[mi][0] = bb.x; acc[mi][1] = bb.y; acc[mi][2] = bb.z; acc[mi][3] = bb.w;
    }

    for (int kk = 0; kk < HH; kk += K_CHUNK) {
        __syncthreads();
#pragma unroll
        for (int i = 0; i < 4; ++i) {
            int s = t + i * 256;
            int node = s >> 3;
            int cpos = (s & 7) * 4;
            int g = m0 + node;
            float4 v = make_float4(0.f, 0.f, 0.f, 0.f);
            if (g < n) v = *(const float4*)&x[(size_t)g * HH + kk + cpos];
            xs[cpos + 0][node] = v.x;
            xs[cpos + 1][node] = v.y;
            xs[cpos + 2][node] = v.z;
            xs[cpos + 3][node] = v.w;
        }
        __syncthreads();
#pragma unroll
        for (int k = 0; k < K_CHUNK; ++k) {
            float4 wv = *(const float4*)&Ws[(kk + k) * DD + tn * 4];
            const float* xr = &xs[k][tm * 8];
            float4 xa = *(const float4*)xr;
            float4 xb = *(const float4*)(xr + 4);
            float xm[8] = {xa.x, xa.y, xa.z, xa.w, xb.x, xb.y, xb.z, xb.w};
            float wj[4] = {wv.x, wv.y, wv.z, wv.w};
#pragma unroll
            for (int mi = 0; mi < 8; ++mi)
#pragma unroll
                for (int j = 0; j < 4; ++j)
                    acc[mi][j] += xm[mi] * wj[j];
        }
    }
#pragma unroll
    for (int mi = 0; mi < 8; ++mi) {
        int node = m0 + tm * 8 + mi;
        if (node >= n) continue;
        ushort4 o;
        o.x = f2h(fmaxf(acc[mi][0], 0.f));
        o.y = f2h(fmaxf(acc[mi][1], 0.f));
        o.z = f2h(fmaxf(acc[mi][2], 0.f));
        o.w = f2h(fmaxf(acc[mi][3], 0.f));
        *(ushort4*)&x0[(size_t)node * DD + tn * 4] = o;
        *(ushort4*)&h[(size_t)node * DD + tn * 4] = o;
    }
}

// Gather/SpMM: z = 0.9*(A@h) + 0.1*x0 (half storage). Group-per-node:
// each 16-lane group owns one node (4 nodes/wave). Register accumulation
// only (round-6 lesson: no LDS atomics on the per-edge path).
__global__ __launch_bounds__(256) void gather_kernel(
    const ushort* __restrict__ h_in, const ushort* __restrict__ x0,
    const int2* __restrict__ rowptr2, const int2* __restrict__ cw,
    ushort* __restrict__ z, int n) {
    __shared__ int2 es[4][64];
    int wave = threadIdx.x >> 6, lane = threadIdx.x & 63;
    int grp = lane >> 4, sub = lane & 15;
    int2* slot = &es[wave][grp * 16];

    for (int nb = (blockIdx.x * 4 + wave) * 4; nb < n; nb += gridDim.x * 16) {
        int node = nb + grp;
        bool nvalid = node < n;
        int nn = nvalid ? node : (n - 1);
        int2 rp = rowptr2[nn];
        int beg = rp.x;
        int end = nvalid ? rp.y : beg;
        uint2 x0v = *(const uint2*)&x0[(size_t)nn * DD + sub * 4];
        float acc[4][4];
#pragma unroll
        for (int c = 0; c < 4; ++c)
#pragma unroll
            for (int f = 0; f < 4; ++f) acc[c][f] = 0.f;

        for (int base = beg; base < end; base += 16) {
            int m = end - base;
            if (m > 16) m = 16;
            if (sub < m) slot[sub] = cw[base + sub];
            // same-wave LDS write->read; compiler orders via lgkmcnt
#pragma unroll
            for (int j = 0; j < 4; ++j) {
#pragma unroll
                for (int c = 0; c < 4; ++c) {
                    int idx = j * 4 + c;
                    bool v = idx < m;
                    int2 r = slot[v ? idx : 0];
                    float w = v ? __int_as_float(r.y) : 0.f;
                    uint2 hv = *(const uint2*)&h_in[(size_t)r.x * DD + sub * 4];
                    acc[c][0] += w * us2f((ushort)(hv.x & 0xffff));
                    acc[c][1] += w * us2f((ushort)(hv.x >> 16));
                    acc[c][2] += w * us2f((ushort)(hv.y & 0xffff));
                    acc[c][3] += w * us2f((ushort)(hv.y >> 16));
                }
            }
        }
        float f0 = (acc[0][0] + acc[1][0]) + (acc[2][0] + acc[3][0]);
        float f1 = (acc[0][1] + acc[1][1]) + (acc[2][1] + acc[3][1]);
        float f2 = (acc[0][2] + acc[1][2]) + (acc[2][2] + acc[3][2]);
        float f3 = (acc[0][3] + acc[1][3]) + (acc[2][3] + acc[3][3]);
        if (nvalid) {
            float z0 = 0.9f * f0 + 0.1f * us2f((ushort)(x0v.x & 0xffff));
            float z1 = 0.9f * f1 + 0.1f * us2f((ushort)(x0v.x >> 16));
            float z2 = 0.9f * f2 + 0.1f * us2f((ushort)(x0v.y & 0xffff));
            float z3 = 0.9f * f3 + 0.1f * us2f((ushort)(x0v.y >> 16));
            uint zlo = (uint)f2h(z0) | ((uint)f2h(z1) << 16);
            uint zhi = (uint)f2h(z2) | ((uint)f2h(z3) << 16);
            *(uint2*)&z[(size_t)node * DD + sub * 4] = make_uint2(zlo, zhi);
        }
    }
}

// h = relu(z @ W'). Tiled GEMM, K=64. Output: half or f32 (final layer).
__global__ __launch_bounds__(256) void dense_kernel(
    const ushort* __restrict__ zin, const float* __restrict__ Wp,
    ushort* __restrict__ h_half, float* __restrict__ h_f32, int n) {
    __shared__ float Ws[DD * DD];
    __shared__ float xs[K_CHUNK][M_TILE + 4];
    for (int i = threadIdx.x; i < DD * DD; i += 256) Ws[i] = Wp[i];

    int t = threadIdx.x;
    int tm = t >> 4, tn = t & 15;
    int m0 = blockIdx.x * M_TILE;

    float acc[8][4];
#pragma unroll
    for (int mi = 0; mi < 8; ++mi)
#pragma unroll
        for (int j = 0; j < 4; ++j) acc[mi][j] = 0.f;

    for (int kk = 0; kk < DD; kk += K_CHUNK) {
        __syncthreads();
#pragma unroll
        for (int i = 0; i < 4; ++i) {
            int s = t + i * 256;
            int node = s >> 3;
            int cpos = (s & 7) * 4;
            int g = m0 + node;
            ushort4 v = make_ushort4(0, 0, 0, 0);
            if (g < n) v = *(const ushort4*)&zin[(size_t)g * DD + kk + cpos];
            xs[cpos + 0][node] = us2f(v.x);
            xs[cpos + 1][node] = us2f(v.y);
            xs[cpos + 2][node] = us2f(v.z);
            xs[cpos + 3][node] = us2f(v.w);
        }
        __syncthreads();
#pragma unroll
        for (int k = 0; k < K_CHUNK; ++k) {
            float4 wv = *(const float4*)&Ws[(kk + k) * DD + tn * 4];
            const float* xr = &xs[k][tm * 8];
            float4 xa = *(const float4*)xr;
            float4 xb = *(const float4*)(xr + 4);
            float xm[8] = {xa.x, xa.y, xa.z, xa.w, xb.x, xb.y, xb.z, xb.w};
            float wj[4] = {wv.x, wv.y, wv.z, wv.w};
#pragma unroll
            for (int mi = 0; mi < 8; ++mi)
#pragma unroll
                for (int j = 0; j < 4; ++j)
                    acc[mi][j] += xm[mi] * wj[j];
        }
    }
#pragma unroll
    for (int mi = 0; mi < 8; ++mi) {
        int node = m0 + tm * 8 + mi;
        if (node >= n) continue;
        float o0 = fmaxf(acc[mi][0], 0.f);
        float o1 = fmaxf(acc[mi][1], 0.f);
        float o2 = fmaxf(acc[mi][2], 0.f);
        float o3 = fmaxf(acc[mi][3], 0.f);
        if (h_f32) {
            *(float4*)&h_f32[(size_t)node * DD + tn * 4] =
                make_float4(o0, o1, o2, o3);
        } else {
            ushort4 o;
            o.x = f2h(o0); o.y = f2h(o1); o.z = f2h(o2); o.w = f2h(o3);
            *(ushort4*)&h_half[(size_t)node * DD + tn * 4] = o;
        }
    }
}

static inline size_t align256(size_t x) { return (x + 255) & ~(size_t)255; }

extern "C" void kernel_launch(void* const* d_in, const int* in_sizes, int n_in,
                              void* d_out, int out_size, void* d_ws, size_t ws_size,
                              hipStream_t stream) {
    const float* x      = (const float*)d_in[0];
    const int*   row    = (const int*)d_in[1];
    const int*   col    = (const int*)d_in[2];
    const float* ew     = (const float*)d_in[3];
    const float* w_lin  = (const float*)d_in[4];
    const float* b_lin  = (const float*)d_in[5];
    const float* conv_w = (const float*)d_in[6];
    float* out = (float*)d_out;

    const int N = in_sizes[0] / HH;          // 100000
    const int E = in_sizes[1];               // 1600000
    const int L = in_sizes[6] / (DD * DD);   // 4
    const int nbuk = (N + NPB - 1) / NPB;    // 782

    char* ws = (char*)d_ws;
    size_t off = 0;
    int* bcur = (int*)(ws + off);        off = align256(off + (size_t)NBUK_MAX * 4);
    uint2* pk = (uint2*)(ws + off);      off = align256(off + (size_t)nbuk * SLOT * 8);
    int2* cw = (int2*)(ws + off);        off = align256(off + (size_t)nbuk * SLOT * 8);
    int2* rowptr2 = (int2*)(ws + off);   off = align256(off + (size_t)N * 8);
    ushort* x0 = (ushort*)(ws + off);    off = align256(off + (size_t)N * DD * 2);
    ushort* hA = (ushort*)(ws + off);    off = align256(off + (size_t)N * DD * 2);
    ushort* hB = (ushort*)(ws + off);    off = align256(off + (size_t)N * DD * 2);
    ushort* zb = (ushort*)(ws + off);    off = align256(off + (size_t)N * DD * 2);
    float* Wp = (float*)(ws + off);      off = align256(off + (size_t)L * DD * DD * 4);
    (void)ws_size;

    const int mt = (N + M_TILE - 1) / M_TILE;

    // ---- CSR build: bucketed counting sort (no random sub-line stores) ----
    init_bcur<<<(nbuk + 255) / 256, 256, 0, stream>>>(bcur, nbuk);
    partition_kernel<<<PART_BLOCKS, PART_THREADS, 0, stream>>>(row, col, ew, bcur, pk, E, nbuk);
    sort_kernel<<<nbuk, 256, 0, stream>>>(pk, bcur, cw, rowptr2, N);

    // ---- premixed layer weights ----
    int total = L * DD * DD;
    prep_w<<<(total + 255) / 256, 256, 0, stream>>>(conv_w, Wp, total);

    // ---- h0 = relu(x @ Wlin + b) -> x0, hA (half) ----
    lin0_kernel<<<mt, 256, 0, stream>>>(x, w_lin, b_lin, x0, hA, N);

    // ---- L layers: gather -> dense; ping-pong hA/hB; final -> f32 out ----
    for (int l = 0; l < L; ++l) {
        const ushort* hin = (l % 2 == 0) ? hA : hB;
        ushort* hout      = (l % 2 == 0) ? hB : hA;
        gather_kernel<<<2048, 256, 0, stream>>>(hin, x0, rowptr2, cw, zb, N);
        bool last = (l == L - 1);
        dense_kernel<<<mt, 256, 0, stream>>>(zb, Wp + (size_t)l * DD * DD,
                                             last ? nullptr : hout,
                                             last ? out : nullptr, N);
    }
}

// Round 10
// 308.953 us; speedup vs baseline: 9.3455x; 1.1051x over previous
//
#include <hip/hip_runtime.h>
#include <hip/hip_fp16.h>
#include <math.h>

// GCNII forward, fp16-compressed intermediates.
//   h0 = relu(x @ Wlin + b)                       [lin0: tiled GEMM]
//   per layer l: z = 0.9*(A@h) + 0.1*x0           [gather: CSR, group-per-node]
//                h = relu(z @ W'_l)               [dense: tiled GEMM]
//   W'_l = (1-beta_l) I + beta_l W_l (premixed).
// Round-10: lin0/dense GEMMs restructured after round-9 counters showed
// 1.2M LDS bank conflicts + 17% occupancy on lin0:
//   - W stays in GLOBAL (L1-resident: each wave re-reads the same 256B/k)
//   - x/z tile in a 16KB XOR-swizzled LDS buffer xs[32][128],
//     phys_col = node ^ (((k>>2)&3)<<3): writes 2 lanes/bank (free),
//     b128 reads conflict-free, float4 alignment preserved.
// CSR build: bucketed counting sort (no random sub-line global stores).
// Constants: N=100000, E=1600000, H=128, D=64, L=4.

#define DD 64
#define HH 128
#define M_TILE 128
#define K_CHUNK 32
#define NPB 128            // nodes per bucket (bucket = node>>7)
#define SLOT 2560          // record slots per bucket (mean ~2046, +11 sigma)
#define NBUK_MAX 1024
#define PART_BLOCKS 256
#define PART_THREADS 1024

__device__ inline ushort f2h(float f) { return __half_as_ushort(__float2half(f)); }
__device__ inline float us2f(ushort u) { return __half2float(__ushort_as_half(u)); }

__global__ __launch_bounds__(256) void init_bcur(int* bcur, int nbuk) {
    int i = blockIdx.x * blockDim.x + threadIdx.x;
    if (i < nbuk) bcur[i] = i * SLOT;
}

// One-pass partition into bucket slots. Record: {row:17 | col_lo15:15},
// {col_hi2:2 | w_fp16:16<<2}.
__global__ __launch_bounds__(PART_THREADS) void partition_kernel(
    const int* __restrict__ row, const int* __restrict__ col,
    const float* __restrict__ ew, int* __restrict__ bcur,
    uint2* __restrict__ pk, int E, int nbuk) {
    __shared__ int cnt[NBUK_MAX], base[NBUK_MAX], rc[NBUK_MAX];
    int t = threadIdx.x;
    for (int i = t; i < nbuk; i += PART_THREADS) { cnt[i] = 0; rc[i] = 0; }
    __syncthreads();
    int chunk = (E + gridDim.x - 1) / gridDim.x;
    int s0 = blockIdx.x * chunk;
    int s1 = min(s0 + chunk, E);
    for (int e = s0 + t; e < s1; e += PART_THREADS)
        atomicAdd(&cnt[__builtin_nontemporal_load(&row[e]) >> 7], 1);
    __syncthreads();
    for (int i = t; i < nbuk; i += PART_THREADS)
        if (cnt[i] > 0) base[i] = atomicAdd(&bcur[i], cnt[i]);
    __syncthreads();
    for (int e = s0 + t; e < s1; e += PART_THREADS) {
        int r = __builtin_nontemporal_load(&row[e]);
        int c = __builtin_nontemporal_load(&col[e]);
        ushort wh = f2h(__builtin_nontemporal_load(&ew[e]));
        int b = r >> 7;
        int pos = base[b] + atomicAdd(&rc[b], 1);
        if (pos < (b + 1) * SLOT)   // defensive (SLOT is +11 sigma)
            pk[pos] = make_uint2((uint)r | (((uint)c & 0x7fffu) << 17),
                                 ((uint)c >> 15) | ((uint)wh << 2));
    }
}

// Per-bucket counting sort -> CSR segment at cw[b*SLOT ..] + rowptr2 pairs.
__global__ __launch_bounds__(256) void sort_kernel(
    const uint2* __restrict__ pk, const int* __restrict__ bcur,
    int2* __restrict__ cw, int2* __restrict__ rowptr2, int n) {
    __shared__ int hist[NPB], scan[NPB], rc[NPB];
    int b = blockIdx.x, lo = b << 7;
    int cnt = min(bcur[b] - b * SLOT, SLOT);
    const uint2* rec = pk + (size_t)b * SLOT;
    int t = threadIdx.x;
    if (t < NPB) { hist[t] = 0; rc[t] = 0; }
    __syncthreads();
    for (int i = t; i < cnt; i += 256)
        atomicAdd(&hist[(rec[i].x & 0x1ffffu) - lo], 1);
    __syncthreads();
    if (t < NPB) scan[t] = hist[t];
    __syncthreads();
    for (int off = 1; off < NPB; off <<= 1) {       // inclusive scan
        int v = (t < NPB && t >= off) ? scan[t - off] : 0;
        __syncthreads();
        if (t < NPB) scan[t] += v;
        __syncthreads();
    }
    if (t < NPB && lo + t < n) {
        int beg = b * SLOT + scan[t] - hist[t];     // exclusive base
        rowptr2[lo + t] = make_int2(beg, beg + hist[t]);
    }
    for (int i = t; i < cnt; i += 256) {
        uint2 r2 = rec[i];
        int nl = (int)(r2.x & 0x1ffffu) - lo;
        int c = (int)((r2.x >> 17) | ((r2.y & 3u) << 15));
        float w = us2f((ushort)((r2.y >> 2) & 0xffffu));
        int pos = (scan[nl] - hist[nl]) + atomicAdd(&rc[nl], 1);
        cw[b * SLOT + pos] = make_int2(c, __float_as_int(w));
    }
}

// W'_l = (1-beta_l) I + beta_l W_l, all L layers at once.
__global__ __launch_bounds__(256) void prep_w(const float* __restrict__ conv_w,
                                              float* __restrict__ Wp, int total) {
    int i = blockIdx.x * blockDim.x + threadIdx.x;
    if (i >= total) return;
    int l = i >> 12;
    int r = i & 4095;
    int d = r >> 6, j = r & 63;
    float beta = logf(0.5f / (float)(l + 1) + 1.0f);
    float v = beta * conv_w[i];
    if (d == j) v += 1.0f - beta;
    Wp[i] = v;
}

// h0 = relu(x @ Wlin + b). Register-tiled GEMM, thread = 8 nodes x 4 outs.
// W from global (L1-hot); x tile in XOR-swizzled 16KB LDS.
__global__ __launch_bounds__(256) void lin0_kernel(
    const float* __restrict__ x, const float* __restrict__ Wlin,
    const float* __restrict__ b, ushort* __restrict__ x0,
    ushort* __restrict__ h, int n) {
    __shared__ float xs[K_CHUNK][M_TILE];      // 16 KB, swizzled columns
    int t = threadIdx.x;
    int tm = t >> 4, tn = t & 15;
    int m0 = blockIdx.x * M_TILE;

    float4 bb = *(const float4*)&b[tn * 4];
    float acc[8][4];
#pragma unroll
    for (int mi = 0; mi < 8; ++mi) {
        acc[mi][0] = bb.x; acc[mi][1] = bb.y; acc[mi][2] = bb.z; acc[mi][3] = bb.w;
    }

    for (int kk = 0; kk < HH; kk += K_CHUNK) {
        __syncthreads();
#pragma unroll
        for (int i = 0; i < 4; ++i) {
            int s = t + i * 256;
            int node = s >> 3;             // 0..127
            int cpos = (s & 7) * 4;        // 0..28
            int g = m0 + node;
            float4 v = make_float4(0.f, 0.f, 0.f, 0.f);
            if (g < n) v = *(const float4*)&x[(size_t)g * HH + kk + cpos];
            int q = (s & 7) & 3;           // = ((cpos+j)>>2)&3 for j<4
            int pc = node ^ (q << 3);      // swizzled column
            xs[cpos + 0][pc] = v.x;
            xs[cpos + 1][pc] = v.y;
            xs[cpos + 2][pc] = v.z;
            xs[cpos + 3][pc] = v.w;
        }
        __syncthreads();
#pragma unroll
        for (int k = 0; k < K_CHUNK; ++k) {
            float4 wv = *(const float4*)&Wlin[(size_t)(kk + k) * DD + tn * 4];
            int base = (tm * 8) ^ ((((k) >> 2) & 3) << 3);
            float4 xa = *(const float4*)&xs[k][base];
            float4 xb = *(const float4*)&xs[k][base + 4];
            float xm[8] = {xa.x, xa.y, xa.z, xa.w, xb.x, xb.y, xb.z, xb.w};
            float wj[4] = {wv.x, wv.y, wv.z, wv.w};
#pragma unroll
            for (int mi = 0; mi < 8; ++mi)
#pragma unroll
                for (int j = 0; j < 4; ++j)
                    acc[mi][j] += xm[mi] * wj[j];
        }
    }
#pragma unroll
    for (int mi = 0; mi < 8; ++mi) {
        int node = m0 + tm * 8 + mi;
        if (node >= n) continue;
        ushort4 o;
        o.x = f2h(fmaxf(acc[mi][0], 0.f));
        o.y = f2h(fmaxf(acc[mi][1], 0.f));
        o.z = f2h(fmaxf(acc[mi][2], 0.f));
        o.w = f2h(fmaxf(acc[mi][3], 0.f));
        *(ushort4*)&x0[(size_t)node * DD + tn * 4] = o;
        *(ushort4*)&h[(size_t)node * DD + tn * 4] = o;
    }
}

// Gather/SpMM: z = 0.9*(A@h) + 0.1*x0 (half storage). Group-per-node:
// each 16-lane group owns one node (4 nodes/wave). Register accumulation
// only (round-6 lesson: no LDS atomics on the per-edge path).
__global__ __launch_bounds__(256) void gather_kernel(
    const ushort* __restrict__ h_in, const ushort* __restrict__ x0,
    const int2* __restrict__ rowptr2, const int2* __restrict__ cw,
    ushort* __restrict__ z, int n) {
    __shared__ int2 es[4][64];
    int wave = threadIdx.x >> 6, lane = threadIdx.x & 63;
    int grp = lane >> 4, sub = lane & 15;
    int2* slot = &es[wave][grp * 16];

    for (int nb = (blockIdx.x * 4 + wave) * 4; nb < n; nb += gridDim.x * 16) {
        int node = nb + grp;
        bool nvalid = node < n;
        int nn = nvalid ? node : (n - 1);
        int2 rp = rowptr2[nn];
        int beg = rp.x;
        int end = nvalid ? rp.y : beg;
        uint2 x0v = *(const uint2*)&x0[(size_t)nn * DD + sub * 4];
        float acc[4][4];
#pragma unroll
        for (int c = 0; c < 4; ++c)
#pragma unroll
            for (int f = 0; f < 4; ++f) acc[c][f] = 0.f;

        for (int base = beg; base < end; base += 16) {
            int m = end - base;
            if (m > 16) m = 16;
            if (sub < m) slot[sub] = cw[base + sub];
            // same-wave LDS write->read; compiler orders via lgkmcnt
#pragma unroll
            for (int j = 0; j < 4; ++j) {
#pragma unroll
                for (int c = 0; c < 4; ++c) {
                    int idx = j * 4 + c;
                    bool v = idx < m;
                    int2 r = slot[v ? idx : 0];
                    float w = v ? __int_as_float(r.y) : 0.f;
                    uint2 hv = *(const uint2*)&h_in[(size_t)r.x * DD + sub * 4];
                    acc[c][0] += w * us2f((ushort)(hv.x & 0xffff));
                    acc[c][1] += w * us2f((ushort)(hv.x >> 16));
                    acc[c][2] += w * us2f((ushort)(hv.y & 0xffff));
                    acc[c][3] += w * us2f((ushort)(hv.y >> 16));
                }
            }
        }
        float f0 = (acc[0][0] + acc[1][0]) + (acc[2][0] + acc[3][0]);
        float f1 = (acc[0][1] + acc[1][1]) + (acc[2][1] + acc[3][1]);
        float f2 = (acc[0][2] + acc[1][2]) + (acc[2][2] + acc[3][2]);
        float f3 = (acc[0][3] + acc[1][3]) + (acc[2][3] + acc[3][3]);
        if (nvalid) {
            float z0 = 0.9f * f0 + 0.1f * us2f((ushort)(x0v.x & 0xffff));
            float z1 = 0.9f * f1 + 0.1f * us2f((ushort)(x0v.x >> 16));
            float z2 = 0.9f * f2 + 0.1f * us2f((ushort)(x0v.y & 0xffff));
            float z3 = 0.9f * f3 + 0.1f * us2f((ushort)(x0v.y >> 16));
            uint zlo = (uint)f2h(z0) | ((uint)f2h(z1) << 16);
            uint zhi = (uint)f2h(z2) | ((uint)f2h(z3) << 16);
            *(uint2*)&z[(size_t)node * DD + sub * 4] = make_uint2(zlo, zhi);
        }
    }
}

// h = relu(z @ W'). Tiled GEMM, K=64; W' from global (L1-hot), z tile in
// XOR-swizzled LDS. Output: half or f32 (final layer).
__global__ __launch_bounds__(256) void dense_kernel(
    const ushort* __restrict__ zin, const float* __restrict__ Wp,
    ushort* __restrict__ h_half, float* __restrict__ h_f32, int n) {
    __shared__ float xs[K_CHUNK][M_TILE];      // 16 KB, swizzled columns
    int t = threadIdx.x;
    int tm = t >> 4, tn = t & 15;
    int m0 = blockIdx.x * M_TILE;

    float acc[8][4];
#pragma unroll
    for (int mi = 0; mi < 8; ++mi)
#pragma unroll
        for (int j = 0; j < 4; ++j) acc[mi][j] = 0.f;

    for (int kk = 0; kk < DD; kk += K_CHUNK) {
        __syncthreads();
#pragma unroll
        for (int i = 0; i < 4; ++i) {
            int s = t + i * 256;
            int node = s >> 3;
            int cpos = (s & 7) * 4;
            int g = m0 + node;
            ushort4 v = make_ushort4(0, 0, 0, 0);
            if (g < n) v = *(const ushort4*)&zin[(size_t)g * DD + kk + cpos];
            int q = (s & 7) & 3;
            int pc = node ^ (q << 3);
            xs[cpos + 0][pc] = us2f(v.x);
            xs[cpos + 1][pc] = us2f(v.y);
            xs[cpos + 2][pc] = us2f(v.z);
            xs[cpos + 3][pc] = us2f(v.w);
        }
        __syncthreads();
#pragma unroll
        for (int k = 0; k < K_CHUNK; ++k) {
            float4 wv = *(const float4*)&Wp[(size_t)(kk + k) * DD + tn * 4];
            int base = (tm * 8) ^ (((k >> 2) & 3) << 3);
            float4 xa = *(const float4*)&xs[k][base];
            float4 xb = *(const float4*)&xs[k][base + 4];
            float xm[8] = {xa.x, xa.y, xa.z, xa.w, xb.x, xb.y, xb.z, xb.w};
            float wj[4] = {wv.x, wv.y, wv.z, wv.w};
#pragma unroll
            for (int mi = 0; mi < 8; ++mi)
#pragma unroll
                for (int j = 0; j < 4; ++j)
                    acc[mi][j] += xm[mi] * wj[j];
        }
    }
#pragma unroll
    for (int mi = 0; mi < 8; ++mi) {
        int node = m0 + tm * 8 + mi;
        if (node >= n) continue;
        float o0 = fmaxf(acc[mi][0], 0.f);
        float o1 = fmaxf(acc[mi][1], 0.f);
        float o2 = fmaxf(acc[mi][2], 0.f);
        float o3 = fmaxf(acc[mi][3], 0.f);
        if (h_f32) {
            *(float4*)&h_f32[(size_t)node * DD + tn * 4] =
                make_float4(o0, o1, o2, o3);
        } else {
            ushort4 o;
            o.x = f2h(o0); o.y = f2h(o1); o.z = f2h(o2); o.w = f2h(o3);
            *(ushort4*)&h_half[(size_t)node * DD + tn * 4] = o;
        }
    }
}

static inline size_t align256(size_t x) { return (x + 255) & ~(size_t)255; }

extern "C" void kernel_launch(void* const* d_in, const int* in_sizes, int n_in,
                              void* d_out, int out_size, void* d_ws, size_t ws_size,
                              hipStream_t stream) {
    const float* x      = (const float*)d_in[0];
    const int*   row    = (const int*)d_in[1];
    const int*   col    = (const int*)d_in[2];
    const float* ew     = (const float*)d_in[3];
    const float* w_lin  = (const float*)d_in[4];
    const float* b_lin  = (const float*)d_in[5];
    const float* conv_w = (const float*)d_in[6];
    float* out = (float*)d_out;

    const int N = in_sizes[0] / HH;          // 100000
    const int E = in_sizes[1];               // 1600000
    const int L = in_sizes[6] / (DD * DD);   // 4
    const int nbuk = (N + NPB - 1) / NPB;    // 782

    char* ws = (char*)d_ws;
    size_t off = 0;
    int* bcur = (int*)(ws + off);        off = align256(off + (size_t)NBUK_MAX * 4);
    uint2* pk = (uint2*)(ws + off);      off = align256(off + (size_t)nbuk * SLOT * 8);
    int2* cw = (int2*)(ws + off);        off = align256(off + (size_t)nbuk * SLOT * 8);
    int2* rowptr2 = (int2*)(ws + off);   off = align256(off + (size_t)N * 8);
    ushort* x0 = (ushort*)(ws + off);    off = align256(off + (size_t)N * DD * 2);
    ushort* hA = (ushort*)(ws + off);    off = align256(off + (size_t)N * DD * 2);
    ushort* hB = (ushort*)(ws + off);    off = align256(off + (size_t)N * DD * 2);
    ushort* zb = (ushort*)(ws + off);    off = align256(off + (size_t)N * DD * 2);
    float* Wp = (float*)(ws + off);      off = align256(off + (size_t)L * DD * DD * 4);
    (void)ws_size;

    const int mt = (N + M_TILE - 1) / M_TILE;

    // ---- CSR build: bucketed counting sort (no random sub-line stores) ----
    init_bcur<<<(nbuk + 255) / 256, 256, 0, stream>>>(bcur, nbuk);
    partition_kernel<<<PART_BLOCKS, PART_THREADS, 0, stream>>>(row, col, ew, bcur, pk, E, nbuk);
    sort_kernel<<<nbuk, 256, 0, stream>>>(pk, bcur, cw, rowptr2, N);

    // ---- premixed layer weights ----
    int total = L * DD * DD;
    prep_w<<<(total + 255) / 256, 256, 0, stream>>>(conv_w, Wp, total);

    // ---- h0 = relu(x @ Wlin + b) -> x0, hA (half) ----
    lin0_kernel<<<mt, 256, 0, stream>>>(x, w_lin, b_lin, x0, hA, N);

    // ---- L layers: gather -> dense; ping-pong hA/hB; final -> f32 out ----
    for (int l = 0; l < L; ++l) {
        const ushort* hin = (l % 2 == 0) ? hA : hB;
        ushort* hout      = (l % 2 == 0) ? hB : hA;
        gather_kernel<<<2048, 256, 0, stream>>>(hin, x0, rowptr2, cw, zb, N);
        bool last = (l == L - 1);
        dense_kernel<<<mt, 256, 0, stream>>>(zb, Wp + (size_t)l * DD * DD,
                                             last ? nullptr : hout,
                                             last ? out : nullptr, N);
    }
}